// Round 15
// baseline (980.603 us; speedup 1.0000x reference)
//
#include <hip/hip_runtime.h>
#include <cmath>

#define Bsz  4096
#define Tlen 512
#define Fnum 17
#define Hdim 32
#define Pnum 8
#define FPn  18
#define G3   96   // 3*Hdim
#define TPAD 8    // extra xT rows so the depth-4 prefetch ring never reads OOB

#define L2E   1.4426950408889634f
#define NL2E (-1.4426950408889634f)
#define TL2E  2.8853900817779268f   // 2*log2(e)

typedef __attribute__((ext_vector_type(8))) short short8v;
typedef __attribute__((ext_vector_type(4))) float float4v;
typedef __attribute__((ext_vector_type(2))) float float2v;

__device__ __forceinline__ float frcp(float x)  { return __builtin_amdgcn_rcpf(x); }
__device__ __forceinline__ float frsq(float x)  { return __builtin_amdgcn_rsqf(x); }
__device__ __forceinline__ float fexp2(float x) { return __builtin_amdgcn_exp2f(x); }
__device__ __forceinline__ float fsigmoid(float x) {
    return frcp(1.0f + fexp2(NL2E * x));
}
// compiler-packed f32 pair ops (backend may select v_pk_* for v2f32 — no inline asm)
__device__ __forceinline__ float2v fma2(float2v a, float2v b, float2v c) {
    return __builtin_elementwise_fma(a, b, c);
}
// RNE float->bf16 bits
__device__ __forceinline__ short bf16b(float x) {
    unsigned u = __float_as_uint(x);
    unsigned r = (u + 0x7FFFu + ((u >> 16) & 1u)) >> 16;
    return (short)r;
}
// packed f32x2 -> bf16x2 (hardware RNE) — proven since R2
__device__ __forceinline__ unsigned cvtpk(float lo, float hi) {
    unsigned r;
    asm("v_cvt_pk_bf16_f32 %0, %1, %2" : "=v"(r) : "v"(lo), "v"(hi));
    return r;
}

// ---------- prep: prototype L2 norms ----------
__global__ void prep_pnorm_kernel(const float* __restrict__ protos, float* __restrict__ pnorm) {
    const int p    = threadIdx.x >> 5;
    const int lane = threadIdx.x & 31;
    float s = 0.0f;
    for (int j = lane; j < FPn * Hdim; j += 32) {
        float v = protos[p * FPn * Hdim + j];
        s = fmaf(v, v, s);
    }
    #pragma unroll
    for (int m = 16; m; m >>= 1) s += __shfl_xor(s, m);
    if (lane == 0) pnorm[p] = sqrtf(s);
}

// ---------- prep: x[B,T,F] -> xT[F,T+TPAD,B] in bf16 ----------
__global__ __launch_bounds__(64)
void xpose_kernel(const float* __restrict__ x, unsigned short* __restrict__ xT) {
    const int b = blockIdx.x * 64 + threadIdx.x;
    const int t = blockIdx.y;
    const float* __restrict__ xp = x + ((size_t)b * Tlen + t) * Fnum;
    #pragma unroll
    for (int ff = 0; ff < Fnum; ++ff)
        xT[(size_t)ff * (Tlen + TPAD) * Bsz + (size_t)t * Bsz + b] = (unsigned short)bf16b(xp[ff]);
}

// ---------- main GRU via chained MFMA (R5-proven math, trans-minimized) -------
// Block = ONE wave = (f, 16-b tile); grid = 256 x 17 (R14 balance, 17 waves/CU).
// Set1: a_m = Ws@h + C1  (C1 = fp32 bias: NL2E*(bih+bhh) for r,z; TL2E*bhh for n)
// Set2 (chained): e_m = Wx@[x] + a_m  for r,z; e_n = Wx@[x] + TL2E*bih_n for n.
// pi(m,rr) = (m>>1)*32 + 8*(rr>>2) + (m&1)*4 + (rr&3)  [R2-validated]
// Gate combine (R5 algebra), SHARED-RCP form (R15): the trans pipe is the
// saturated resource (~40 trans/step at quarter rate ~= 100% of wall across
// resident waves; VALUBusy plateau 63% across R5/R13/R14 = trans ceiling).
// Both rcp PAIRS collapse via 1/a = b*rcp(a*b):
//   r pair:  Rr = rcp(rp.x*rp.y); r = {rp.y*Rr, rp.x*Rr}
//   divide:  Rd = rcp(den.x*den.y); h' = {num.x*den.y*Rd, num.y*den.x*Rd}
// => 8 trans/pair (was 10), 32/step (was 40).  Products <= 2^60, safe.
// Codegen rules learned: fragments built fresh inside the step (R8); NO setprio
// (R9); chained MFMA beats VALU-ih (R12); bits-feed + stagger (R13).
template<int USE_XT>
__global__ __launch_bounds__(64, 4)
void gru_mfma_kernel(const float* __restrict__ x,
                     const unsigned short* __restrict__ xT,
                     const float* __restrict__ Wih,   // [F,96]
                     const float* __restrict__ Whh,   // [F,96,32]
                     const float* __restrict__ bih,   // [F,96]
                     const float* __restrict__ bhh,   // [F,96]
                     float* __restrict__ pre)         // [B,18,32]
{
    // de-sync co-SIMD waves; timing-only, output-deterministic.
    for (int i = (blockIdx.x & 7); i > 0; --i) __builtin_amdgcn_s_sleep(1);

    const int f  = blockIdx.y;
    const int l  = threadIdx.x;
    const int c  = l & 15, S = l >> 4;
    const int b  = blockIdx.x * 16 + c;

    const float* __restrict__ whh_f = Whh + (size_t)f * G3 * Hdim;
    const float* __restrict__ wih_f = Wih + (size_t)f * G3;
    const float* __restrict__ bih_f = bih + (size_t)f * G3;
    const float* __restrict__ bhh_f = bhh + (size_t)f * G3;

    // ---- one-time per-lane constants ----
    short8v af0, af1, af2, af3, af4, af5;       // Whh fragments (set1)
    short8v g0, g1, g2, g3, g4, g5;             // Wih fragments (set2, k=0 col)
    float4v cin0, cin1, cin2, cin3, cin4, cin5; // fp32 set1 C (bias)
    float4v cb4, cb5;                           // fp32 set2 C for n tiles
    {
        union { short8v s; unsigned u[4]; } au, gu;
        #pragma unroll
        for (int m = 0; m < 6; ++m) {
            const int gate = m >> 1;
            const float sc = (gate < 2) ? NL2E : TL2E;
            const int gA = gate * 32 + 8 * (c >> 2) + (m & 1) * 4 + (c & 3);
            const float* wrow = whh_f + (size_t)gA * Hdim + 8 * S;
            #pragma unroll
            for (int u = 0; u < 4; ++u)
                au.u[u] = cvtpk(wrow[2 * u] * sc, wrow[2 * u + 1] * sc);
            gu.u[0] = (S == 0) ? cvtpk(sc * wih_f[gA], 0.0f) : 0u;
            gu.u[1] = 0u; gu.u[2] = 0u; gu.u[3] = 0u;
            float4v ci;
            #pragma unroll
            for (int q = 0; q < 4; ++q) {
                const int gC = gate * 32 + 8 * S + (m & 1) * 4 + q;
                ci[q] = (gate < 2) ? NL2E * (bhh_f[gC] + bih_f[gC])
                                   : TL2E * bhh_f[gC];
            }
            if (m == 0) { af0 = au.s; g0 = gu.s; cin0 = ci; }
            if (m == 1) { af1 = au.s; g1 = gu.s; cin1 = ci; }
            if (m == 2) { af2 = au.s; g2 = gu.s; cin2 = ci; }
            if (m == 3) { af3 = au.s; g3 = gu.s; cin3 = ci; }
            if (m == 4) { af4 = au.s; g4 = gu.s; cin4 = ci; }
            if (m == 5) { af5 = au.s; g5 = gu.s; cin5 = ci; }
        }
        #pragma unroll
        for (int q = 0; q < 4; ++q) {
            cb4[q] = TL2E * bih_f[64 + 8 * S + q];
            cb5[q] = TL2E * bih_f[64 + 8 * S + 4 + q];
        }
    }
    const unsigned msk = (S == 0) ? 0xFFFFu : 0u;   // only S=0 lanes feed k=0 of B2

    float2v h0 = {0,0}, h1 = {0,0}, h2 = {0,0}, h3 = {0,0};

    // ---- x prefetch ring, depth 4 (phase-relative offsets), raw bf16 bits ----
    const unsigned short* xtp = USE_XT ? (xT + (size_t)f * (Tlen + TPAD) * Bsz + b) : nullptr;
    const float* xp = USE_XT ? nullptr : (x + (size_t)b * Tlen * Fnum + f);
    unsigned x0, x1, x2, x3;
    if (USE_XT) {
        x0 = xtp[0 * Bsz]; x1 = xtp[1 * Bsz]; x2 = xtp[2 * Bsz]; x3 = xtp[3 * Bsz];
    } else {
        x0 = (unsigned short)bf16b(xp[0 * Fnum]);
        x1 = (unsigned short)bf16b(xp[1 * Fnum]);
        x2 = (unsigned short)bf16b(xp[2 * Fnum]);
        x3 = (unsigned short)bf16b(xp[3 * Fnum]);
    }

// ph is relative to the CURRENT xtp/xp (which corresponds to loop time t)
#define LOADX(ph) (USE_XT ? (unsigned)xtp[(size_t)(ph) * Bsz]                        \
                          : ((t + (ph) < Tlen) ? (unsigned)(unsigned short)bf16b(xp[(size_t)(ph) * Fnum]) : 0u))

// R5 gate algebra, shared-rcp form (8 trans/pair):
//   er = 2^ar; rp = 1+er; Rr = rcp(rp.x*rp.y); r = {rp.y*Rr, rp.x*Rr}
//   ez = 2^az; y = r*an + en; E = 2^y
//   num = ez*(E-1) + h*(E+1); den = (E+1)(ez+1)
//   Rd = rcp(den.x*den.y); h' = {num.x*den.y*Rd, num.y*den.x*Rd}
#define GATE_PAIR(hp, ar, az, an, en)                                           \
    {                                                                           \
        const float2v _ar = (ar), _az = (az), _an = (an), _en = (en);           \
        float2v er = {fexp2(_ar.x), fexp2(_ar.y)};                              \
        float2v rp = er + (float2v){1.0f, 1.0f};                                \
        const float Rr = frcp(rp.x * rp.y);                                     \
        float2v r  = {rp.y * Rr, rp.x * Rr};                                    \
        float2v ez = {fexp2(_az.x), fexp2(_az.y)};                              \
        float2v y  = fma2(r, _an, _en);                                         \
        float2v E  = {fexp2(y.x), fexp2(y.y)};                                  \
        float2v num = fma2(ez, E, -ez) + fma2(hp, E, hp);                       \
        float2v den = (E + (float2v){1.0f, 1.0f}) * (ez + (float2v){1.0f, 1.0f});\
        const float Rd = frcp(den.x * den.y);                                   \
        hp = (float2v){num.x * (den.y * Rd), num.y * (den.x * Rd)};             \
    }

#define LO2(v) ((float2v){(v)[0], (v)[1]})
#define HI2(v) ((float2v){(v)[2], (v)[3]})

#define GRU_STEP(xbits)                                                          \
    {                                                                            \
        union { short8v s; unsigned u[4]; } bu;                                  \
        bu.u[0] = cvtpk(h0.x, h0.y);                                             \
        bu.u[1] = cvtpk(h1.x, h1.y);                                             \
        bu.u[2] = cvtpk(h2.x, h2.y);                                             \
        bu.u[3] = cvtpk(h3.x, h3.y);                                             \
        union { short8v s; unsigned u[4]; } b2;                                  \
        b2.u[0] = (xbits) & msk;                                                 \
        b2.u[1] = 0u; b2.u[2] = 0u; b2.u[3] = 0u;                                \
        const float4v a0 = __builtin_amdgcn_mfma_f32_16x16x32_bf16(af0, bu.s, cin0, 0, 0, 0); \
        const float4v a1 = __builtin_amdgcn_mfma_f32_16x16x32_bf16(af1, bu.s, cin1, 0, 0, 0); \
        const float4v a2 = __builtin_amdgcn_mfma_f32_16x16x32_bf16(af2, bu.s, cin2, 0, 0, 0); \
        const float4v a3 = __builtin_amdgcn_mfma_f32_16x16x32_bf16(af3, bu.s, cin3, 0, 0, 0); \
        const float4v a4 = __builtin_amdgcn_mfma_f32_16x16x32_bf16(af4, bu.s, cin4, 0, 0, 0); \
        const float4v a5 = __builtin_amdgcn_mfma_f32_16x16x32_bf16(af5, bu.s, cin5, 0, 0, 0); \
        const float4v e0 = __builtin_amdgcn_mfma_f32_16x16x32_bf16(g0, b2.s, a0, 0, 0, 0); \
        const float4v e1 = __builtin_amdgcn_mfma_f32_16x16x32_bf16(g1, b2.s, a1, 0, 0, 0); \
        const float4v e2 = __builtin_amdgcn_mfma_f32_16x16x32_bf16(g2, b2.s, a2, 0, 0, 0); \
        const float4v e3 = __builtin_amdgcn_mfma_f32_16x16x32_bf16(g3, b2.s, a3, 0, 0, 0); \
        const float4v e4 = __builtin_amdgcn_mfma_f32_16x16x32_bf16(g4, b2.s, cb4, 0, 0, 0); \
        const float4v e5 = __builtin_amdgcn_mfma_f32_16x16x32_bf16(g5, b2.s, cb5, 0, 0, 0); \
        GATE_PAIR(h0, LO2(e0), LO2(e2), LO2(a4), LO2(e4));                       \
        GATE_PAIR(h1, HI2(e0), HI2(e2), HI2(a4), HI2(e4));                       \
        GATE_PAIR(h2, LO2(e1), LO2(e3), LO2(a5), LO2(e5));                       \
        GATE_PAIR(h3, HI2(e1), HI2(e3), HI2(a5), HI2(e5));                       \
    }

    #pragma unroll 1
    for (int t = 0; t < Tlen; t += 4) {
        GRU_STEP(x0); x0 = LOADX(4);
        GRU_STEP(x1); x1 = LOADX(5);
        GRU_STEP(x2); x2 = LOADX(6);
        GRU_STEP(x3); x3 = LOADX(7);
        if (USE_XT) xtp += 4 * Bsz; else xp += 4 * Fnum;
    }

    float* __restrict__ o = pre + (size_t)b * (FPn * Hdim) + f * Hdim + 8 * S;
    o[0] = h0.x; o[1] = h0.y; o[2] = h1.x; o[3] = h1.y;
    o[4] = h2.x; o[5] = h2.y; o[6] = h3.x; o[7] = h3.y;
#undef GRU_STEP
#undef GATE_PAIR
#undef LOADX
#undef LO2
#undef HI2
}

// ---------- epilogue: 4 waves/block, 1 wave per b.  lane = (h = l&31, f-halfset = l>>5)
__global__ __launch_bounds__(256)
void post_kernel(const float* __restrict__ pre,     // [B,18,32] (f<17 valid)
                 const float* __restrict__ statics, // [B,4]
                 const float* __restrict__ demoW,   // [32,4]
                 const float* __restrict__ demob,   // [32]
                 const float* __restrict__ lnw,     // [18,32]
                 const float* __restrict__ lnb,     // [18,32]
                 const float* __restrict__ protos,  // [8,576]
                 const float* __restrict__ pnorm,   // [8]
                 const float* __restrict__ Wq,      // [32,8]
                 const float* __restrict__ bq,      // [32]
                 const float* __restrict__ Wk,      // [8,18]
                 const float* __restrict__ bk,      // [8]
                 const float* __restrict__ Wv,      // [8,18]
                 const float* __restrict__ bv,      // [8]
                 const float* __restrict__ outW,    // [32]
                 const float* __restrict__ outb,    // [1]
                 float* __restrict__ out_logits,    // [B]
                 float* __restrict__ out_dist,      // [B,8]
                 float* __restrict__ out_ht)        // [B,18,32]
{
    const int b     = blockIdx.x * 4 + (threadIdx.x >> 6);
    const int l     = threadIdx.x & 63;
    const int hl    = l & 31;
    const int fbase = (l >> 5) * 9;

    float v[9];
    #pragma unroll
    for (int j = 0; j < 9; ++j) {
        const int fj = fbase + j;
        if (fj == 17) {
            float acc = demob[hl];
            #pragma unroll
            for (int d = 0; d < 4; ++d)
                acc = fmaf(statics[b * 4 + d], demoW[hl * 4 + d], acc);
            v[j] = acc;
        } else {
            v[j] = pre[(size_t)b * 576 + fj * 32 + hl];
        }
    }

    float s = 0.0f, ss = 0.0f;
    #pragma unroll
    for (int j = 0; j < 9; ++j) { s += v[j]; ss = fmaf(v[j], v[j], ss); }
    #pragma unroll
    for (int m = 32; m; m >>= 1) { s += __shfl_xor(s, m); ss += __shfl_xor(ss, m); }
    const float mu  = s * (1.0f / 576.0f);
    const float var = ss * (1.0f / 576.0f) - mu * mu;
    const float rs  = frsq(var + 1e-5f);

    float nrm = 0.0f;
    #pragma unroll
    for (int j = 0; j < 9; ++j) {
        const int fj = fbase + j;
        float y = fmaf((v[j] - mu) * rs, lnw[fj * 32 + hl], lnb[fj * 32 + hl]);
        v[j] = y;
        out_ht[(size_t)b * 576 + fj * 32 + hl] = y;
        nrm = fmaf(y, y, nrm);
    }
    #pragma unroll
    for (int m = 32; m; m >>= 1) nrm += __shfl_xor(nrm, m);
    nrm = sqrtf(nrm);

    float dist[8];
    #pragma unroll
    for (int p = 0; p < Pnum; ++p) {
        float d = 0.0f;
        #pragma unroll
        for (int j = 0; j < 9; ++j)
            d = fmaf(v[j], protos[p * 576 + (fbase + j) * 32 + hl], d);
        #pragma unroll
        for (int m = 32; m; m >>= 1) d += __shfl_xor(d, m);
        dist[p] = d / fmaxf(nrm * pnorm[p], 1e-8f);
    }
    if (l == 0) {
        #pragma unroll
        for (int p = 0; p < Pnum; ++p) out_dist[(size_t)b * Pnum + p] = dist[p];
    }

    float q = bq[hl];
    #pragma unroll
    for (int p = 0; p < Pnum; ++p) q = fmaf(dist[p], Wq[hl * 8 + p], q);
    float Sq = q;
    #pragma unroll
    for (int m = 16; m; m >>= 1) Sq += __shfl_xor(Sq, m);

    float sf[9], so[9];
    #pragma unroll
    for (int j = 0; j < 9; ++j) {
        float t = v[j] * q;
        #pragma unroll
        for (int m = 16; m; m >>= 1) t += __shfl_xor(t, m);
        sf[j] = t;
    }
    #pragma unroll
    for (int j = 0; j < 9; ++j) so[j] = __shfl_xor(sf[j], 32);
    const int obase = 9 - fbase;

    float e[8];
    #pragma unroll
    for (int p = 0; p < Pnum; ++p) {
        float a = bk[p] * Sq;
        #pragma unroll
        for (int j = 0; j < 9; ++j) {
            a = fmaf(sf[j], Wk[p * FPn + fbase + j], a);
            a = fmaf(so[j], Wk[p * FPn + obase + j], a);
        }
        e[p] = a;
    }
    float mx = e[0];
    #pragma unroll
    for (int p = 1; p < Pnum; ++p) mx = fmaxf(mx, e[p]);
    float aw[8], den = 0.0f;
    #pragma unroll
    for (int p = 0; p < Pnum; ++p) { aw[p] = __expf(e[p] - mx); den += aw[p]; }
    const float rden = frcp(den);
    #pragma unroll
    for (int p = 0; p < Pnum; ++p) aw[p] *= rden;

    float cc = 0.0f;
    #pragma unroll
    for (int p = 0; p < Pnum; ++p) cc = fmaf(aw[p], bv[p], cc);
    float vb = 0.0f;
    #pragma unroll
    for (int j = 0; j < 9; ++j) {
        float wv = 0.0f;
        #pragma unroll
        for (int p = 0; p < Pnum; ++p) wv = fmaf(aw[p], Wv[p * FPn + fbase + j], wv);
        vb = fmaf(v[j], wv, vb);
    }
    vb += __shfl_xor(vb, 32);
    vb += cc;

    float lg = vb * outW[hl];
    #pragma unroll
    for (int m = 16; m; m >>= 1) lg += __shfl_xor(lg, m);
    lg = fsigmoid(lg + outb[0]);
    if (l == 0) out_logits[b] = lg;
}

extern "C" void kernel_launch(void* const* d_in, const int* in_sizes, int n_in,
                              void* d_out, int out_size, void* d_ws, size_t ws_size,
                              hipStream_t stream) {
    const float* x      = (const float*)d_in[0];
    const float* statics= (const float*)d_in[1];
    const float* Wih    = (const float*)d_in[2];
    const float* Whh    = (const float*)d_in[3];
    const float* bih    = (const float*)d_in[4];
    const float* bhh    = (const float*)d_in[5];
    const float* demoW  = (const float*)d_in[6];
    const float* demob  = (const float*)d_in[7];
    const float* lnw    = (const float*)d_in[8];
    const float* lnb    = (const float*)d_in[9];
    const float* protos = (const float*)d_in[10];
    const float* Wq     = (const float*)d_in[11];
    const float* bq     = (const float*)d_in[12];
    const float* Wk     = (const float*)d_in[13];
    const float* bk     = (const float*)d_in[14];
    const float* Wv     = (const float*)d_in[15];
    const float* bv     = (const float*)d_in[16];
    const float* outW   = (const float*)d_in[17];
    const float* outb   = (const float*)d_in[18];

    // ws layout: pre[B*576] f32 | pnorm[8] f32 | xT[F,T+TPAD,B] bf16
    float* pre   = (float*)d_ws;
    float* pnorm = pre + (size_t)Bsz * FPn * Hdim;
    unsigned short* xT = (unsigned short*)(pnorm + 8);
    const size_t need = ((size_t)Bsz * FPn * Hdim + 8) * 4
                      + (size_t)Fnum * (Tlen + TPAD) * Bsz * 2;
    const bool use_xt = (ws_size >= need);

    prep_pnorm_kernel<<<dim3(1), dim3(256), 0, stream>>>(protos, pnorm);

    if (use_xt) {
        xpose_kernel<<<dim3(Bsz / 64, Tlen), dim3(64), 0, stream>>>(x, xT);
        gru_mfma_kernel<1><<<dim3(Bsz / 16, Fnum), dim3(64), 0, stream>>>(
            x, xT, Wih, Whh, bih, bhh, pre);
    } else {
        gru_mfma_kernel<0><<<dim3(Bsz / 16, Fnum), dim3(64), 0, stream>>>(
            x, xT, Wih, Whh, bih, bhh, pre);
    }

    float* out_logits = (float*)d_out;
    float* out_dist   = out_logits + Bsz;
    float* out_ht     = out_dist + (size_t)Bsz * Pnum;

    post_kernel<<<dim3(Bsz / 4), dim3(256), 0, stream>>>(
        pre, statics, demoW, demob, lnw, lnb, protos, pnorm,
        Wq, bq, Wk, bk, Wv, bv, outW, outb,
        out_logits, out_dist, out_ht);
}

// Round 16
// 837.902 us; speedup vs baseline: 1.1703x; 1.1703x over previous
//
#include <hip/hip_runtime.h>
#include <cmath>

#define Bsz  4096
#define Tlen 512
#define Fnum 17
#define Hdim 32
#define Pnum 8
#define FPn  18
#define G3   96   // 3*Hdim
#define TPAD 8    // extra xT rows so the depth-4 prefetch ring never reads OOB

#define L2E   1.4426950408889634f
#define NL2E (-1.4426950408889634f)
#define TL2E  2.8853900817779268f   // 2*log2(e)

typedef __attribute__((ext_vector_type(8))) short short8v;
typedef __attribute__((ext_vector_type(4))) float float4v;
typedef __attribute__((ext_vector_type(2))) float float2v;

__device__ __forceinline__ float frcp(float x)  { return __builtin_amdgcn_rcpf(x); }
__device__ __forceinline__ float frsq(float x)  { return __builtin_amdgcn_rsqf(x); }
__device__ __forceinline__ float fexp2(float x) { return __builtin_amdgcn_exp2f(x); }
__device__ __forceinline__ float fsigmoid(float x) {
    return frcp(1.0f + fexp2(NL2E * x));
}
// compiler-packed f32 pair ops (backend may select v_pk_* for v2f32 — no inline asm)
__device__ __forceinline__ float2v fma2(float2v a, float2v b, float2v c) {
    return __builtin_elementwise_fma(a, b, c);
}
// RNE float->bf16 bits
__device__ __forceinline__ short bf16b(float x) {
    unsigned u = __float_as_uint(x);
    unsigned r = (u + 0x7FFFu + ((u >> 16) & 1u)) >> 16;
    return (short)r;
}
// packed f32x2 -> bf16x2 (hardware RNE) — proven since R2
__device__ __forceinline__ unsigned cvtpk(float lo, float hi) {
    unsigned r;
    asm("v_cvt_pk_bf16_f32 %0, %1, %2" : "=v"(r) : "v"(lo), "v"(hi));
    return r;
}

// ---------- prep: prototype L2 norms ----------
__global__ void prep_pnorm_kernel(const float* __restrict__ protos, float* __restrict__ pnorm) {
    const int p    = threadIdx.x >> 5;
    const int lane = threadIdx.x & 31;
    float s = 0.0f;
    for (int j = lane; j < FPn * Hdim; j += 32) {
        float v = protos[p * FPn * Hdim + j];
        s = fmaf(v, v, s);
    }
    #pragma unroll
    for (int m = 16; m; m >>= 1) s += __shfl_xor(s, m);
    if (lane == 0) pnorm[p] = sqrtf(s);
}

// ---------- prep: x[B,T,F] -> xT[F,T+TPAD,B] in bf16 ----------
__global__ __launch_bounds__(64)
void xpose_kernel(const float* __restrict__ x, unsigned short* __restrict__ xT) {
    const int b = blockIdx.x * 64 + threadIdx.x;
    const int t = blockIdx.y;
    const float* __restrict__ xp = x + ((size_t)b * Tlen + t) * Fnum;
    #pragma unroll
    for (int ff = 0; ff < Fnum; ++ff)
        xT[(size_t)ff * (Tlen + TPAD) * Bsz + (size_t)t * Bsz + b] = (unsigned short)bf16b(xp[ff]);
}

// ---------- main GRU via chained MFMA (R5-proven math) ------------------------
// Block = ONE wave = (f, 16-b tile); grid = 256 x 17 = 4352 blocks = exactly
// 17 waves/CU (R14 geometry — the measured optimum: 839.6 us total).
// Set1: a_m = Ws@h + C1  (C1 = fp32 bias: NL2E*(bih+bhh) for r,z; TL2E*bhh for n)
// Set2 (chained): e_m = Wx@[x] + a_m  for r,z; e_n = Wx@[x] + TL2E*bih_n for n.
// pi(m,rr) = (m>>1)*32 + 8*(rr>>2) + (m&1)*4 + (rr&3)  [R2-validated]
// Gate combine (R5 exact form): E=e^{2y}, ez=e^{-zhat}:
//   h' = [ez*(E-1) + h*(E+1)] / [(E+1)*(1+ez)]   (per-element rcp)
// Session lessons encoded here:
//  R8:  fragment unions built fresh inside the step (hoisted partial -> scratch)
//  R9:  no setprio in this reg-tight loop (fences MFMA cluster -> spill)
//  R10/R11: if restructuring, use bit_cast not unions (this exact form is
//           union-based and proven; do not partially rewrite it)
//  R12: chained MFMA > VALU-ih (MFMA issue is free; VALU is the scarce pipe)
//  R15: do NOT share rcps across packed components (scalarizes v_pk_* and
//       deepens the serial chain; -15%)
//  R3/R11/R14: waves up / ILP-2 / balance all null-or-negative -> this step
//       composition is the local optimum (~615 busy cyc/step + latency residue)
template<int USE_XT>
__global__ __launch_bounds__(64, 4)
void gru_mfma_kernel(const float* __restrict__ x,
                     const unsigned short* __restrict__ xT,
                     const float* __restrict__ Wih,   // [F,96]
                     const float* __restrict__ Whh,   // [F,96,32]
                     const float* __restrict__ bih,   // [F,96]
                     const float* __restrict__ bhh,   // [F,96]
                     float* __restrict__ pre)         // [B,18,32]
{
    // de-sync co-SIMD waves (distinct blockIdx.x); timing-only.
    for (int i = (blockIdx.x & 7); i > 0; --i) __builtin_amdgcn_s_sleep(1);

    const int f  = blockIdx.y;
    const int l  = threadIdx.x;
    const int c  = l & 15, S = l >> 4;
    const int b  = blockIdx.x * 16 + c;

    const float* __restrict__ whh_f = Whh + (size_t)f * G3 * Hdim;
    const float* __restrict__ wih_f = Wih + (size_t)f * G3;
    const float* __restrict__ bih_f = bih + (size_t)f * G3;
    const float* __restrict__ bhh_f = bhh + (size_t)f * G3;

    // ---- one-time per-lane constants ----
    short8v af0, af1, af2, af3, af4, af5;       // Whh fragments (set1)
    short8v g0, g1, g2, g3, g4, g5;             // Wih fragments (set2, k=0 col)
    float4v cin0, cin1, cin2, cin3, cin4, cin5; // fp32 set1 C (bias)
    float4v cb4, cb5;                           // fp32 set2 C for n tiles
    {
        union { short8v s; unsigned u[4]; } au, gu;
        #pragma unroll
        for (int m = 0; m < 6; ++m) {
            const int gate = m >> 1;
            const float sc = (gate < 2) ? NL2E : TL2E;
            const int gA = gate * 32 + 8 * (c >> 2) + (m & 1) * 4 + (c & 3);
            const float* wrow = whh_f + (size_t)gA * Hdim + 8 * S;
            #pragma unroll
            for (int u = 0; u < 4; ++u)
                au.u[u] = cvtpk(wrow[2 * u] * sc, wrow[2 * u + 1] * sc);
            gu.u[0] = (S == 0) ? cvtpk(sc * wih_f[gA], 0.0f) : 0u;
            gu.u[1] = 0u; gu.u[2] = 0u; gu.u[3] = 0u;
            float4v ci;
            #pragma unroll
            for (int q = 0; q < 4; ++q) {
                const int gC = gate * 32 + 8 * S + (m & 1) * 4 + q;
                ci[q] = (gate < 2) ? NL2E * (bhh_f[gC] + bih_f[gC])
                                   : TL2E * bhh_f[gC];
            }
            if (m == 0) { af0 = au.s; g0 = gu.s; cin0 = ci; }
            if (m == 1) { af1 = au.s; g1 = gu.s; cin1 = ci; }
            if (m == 2) { af2 = au.s; g2 = gu.s; cin2 = ci; }
            if (m == 3) { af3 = au.s; g3 = gu.s; cin3 = ci; }
            if (m == 4) { af4 = au.s; g4 = gu.s; cin4 = ci; }
            if (m == 5) { af5 = au.s; g5 = gu.s; cin5 = ci; }
        }
        #pragma unroll
        for (int q = 0; q < 4; ++q) {
            cb4[q] = TL2E * bih_f[64 + 8 * S + q];
            cb5[q] = TL2E * bih_f[64 + 8 * S + 4 + q];
        }
    }
    const unsigned msk = (S == 0) ? 0xFFFFu : 0u;   // only S=0 lanes feed k=0 of B2

    float2v h0 = {0,0}, h1 = {0,0}, h2 = {0,0}, h3 = {0,0};

    // ---- x prefetch ring, depth 4 (phase-relative offsets), raw bf16 bits ----
    const unsigned short* xtp = USE_XT ? (xT + (size_t)f * (Tlen + TPAD) * Bsz + b) : nullptr;
    const float* xp = USE_XT ? nullptr : (x + (size_t)b * Tlen * Fnum + f);
    unsigned x0, x1, x2, x3;
    if (USE_XT) {
        x0 = xtp[0 * Bsz]; x1 = xtp[1 * Bsz]; x2 = xtp[2 * Bsz]; x3 = xtp[3 * Bsz];
    } else {
        x0 = (unsigned short)bf16b(xp[0 * Fnum]);
        x1 = (unsigned short)bf16b(xp[1 * Fnum]);
        x2 = (unsigned short)bf16b(xp[2 * Fnum]);
        x3 = (unsigned short)bf16b(xp[3 * Fnum]);
    }

// ph is relative to the CURRENT xtp/xp (which corresponds to loop time t)
#define LOADX(ph) (USE_XT ? (unsigned)xtp[(size_t)(ph) * Bsz]                        \
                          : ((t + (ph) < Tlen) ? (unsigned)(unsigned short)bf16b(xp[(size_t)(ph) * Fnum]) : 0u))

// R5-proven gate combine, per packed pair (verbatim — independent per-element
// rcps keep the v_pk_* packing and the shortest serial chain; see R15 lesson)
#define GATE_PAIR(hp, ar, az, an, en)                                           \
    {                                                                           \
        const float2v _ar = (ar), _az = (az), _an = (an), _en = (en);           \
        float2v er = {fexp2(_ar.x), fexp2(_ar.y)};                              \
        float2v rp = er + (float2v){1.0f, 1.0f};                                \
        float2v r  = {frcp(rp.x), frcp(rp.y)};                                  \
        float2v ez = {fexp2(_az.x), fexp2(_az.y)};                              \
        float2v y  = fma2(r, _an, _en);                                         \
        float2v E  = {fexp2(y.x), fexp2(y.y)};                                  \
        float2v num = fma2(ez, E, -ez) + fma2(hp, E, hp);                       \
        float2v den = (E + (float2v){1.0f, 1.0f}) * (ez + (float2v){1.0f, 1.0f});\
        float2v rd = {frcp(den.x), frcp(den.y)};                                \
        hp = num * rd;                                                          \
    }

#define LO2(v) ((float2v){(v)[0], (v)[1]})
#define HI2(v) ((float2v){(v)[2], (v)[3]})

#define GRU_STEP(xbits)                                                          \
    {                                                                            \
        union { short8v s; unsigned u[4]; } bu;                                  \
        bu.u[0] = cvtpk(h0.x, h0.y);                                             \
        bu.u[1] = cvtpk(h1.x, h1.y);                                             \
        bu.u[2] = cvtpk(h2.x, h2.y);                                             \
        bu.u[3] = cvtpk(h3.x, h3.y);                                             \
        union { short8v s; unsigned u[4]; } b2;                                  \
        b2.u[0] = (xbits) & msk;                                                 \
        b2.u[1] = 0u; b2.u[2] = 0u; b2.u[3] = 0u;                                \
        const float4v a0 = __builtin_amdgcn_mfma_f32_16x16x32_bf16(af0, bu.s, cin0, 0, 0, 0); \
        const float4v a1 = __builtin_amdgcn_mfma_f32_16x16x32_bf16(af1, bu.s, cin1, 0, 0, 0); \
        const float4v a2 = __builtin_amdgcn_mfma_f32_16x16x32_bf16(af2, bu.s, cin2, 0, 0, 0); \
        const float4v a3 = __builtin_amdgcn_mfma_f32_16x16x32_bf16(af3, bu.s, cin3, 0, 0, 0); \
        const float4v a4 = __builtin_amdgcn_mfma_f32_16x16x32_bf16(af4, bu.s, cin4, 0, 0, 0); \
        const float4v a5 = __builtin_amdgcn_mfma_f32_16x16x32_bf16(af5, bu.s, cin5, 0, 0, 0); \
        const float4v e0 = __builtin_amdgcn_mfma_f32_16x16x32_bf16(g0, b2.s, a0, 0, 0, 0); \
        const float4v e1 = __builtin_amdgcn_mfma_f32_16x16x32_bf16(g1, b2.s, a1, 0, 0, 0); \
        const float4v e2 = __builtin_amdgcn_mfma_f32_16x16x32_bf16(g2, b2.s, a2, 0, 0, 0); \
        const float4v e3 = __builtin_amdgcn_mfma_f32_16x16x32_bf16(g3, b2.s, a3, 0, 0, 0); \
        const float4v e4 = __builtin_amdgcn_mfma_f32_16x16x32_bf16(g4, b2.s, cb4, 0, 0, 0); \
        const float4v e5 = __builtin_amdgcn_mfma_f32_16x16x32_bf16(g5, b2.s, cb5, 0, 0, 0); \
        GATE_PAIR(h0, LO2(e0), LO2(e2), LO2(a4), LO2(e4));                       \
        GATE_PAIR(h1, HI2(e0), HI2(e2), HI2(a4), HI2(e4));                       \
        GATE_PAIR(h2, LO2(e1), LO2(e3), LO2(a5), LO2(e5));                       \
        GATE_PAIR(h3, HI2(e1), HI2(e3), HI2(a5), HI2(e5));                       \
    }

    #pragma unroll 1
    for (int t = 0; t < Tlen; t += 4) {
        GRU_STEP(x0); x0 = LOADX(4);
        GRU_STEP(x1); x1 = LOADX(5);
        GRU_STEP(x2); x2 = LOADX(6);
        GRU_STEP(x3); x3 = LOADX(7);
        if (USE_XT) xtp += 4 * Bsz; else xp += 4 * Fnum;
    }

    float* __restrict__ o = pre + (size_t)b * (FPn * Hdim) + f * Hdim + 8 * S;
    o[0] = h0.x; o[1] = h0.y; o[2] = h1.x; o[3] = h1.y;
    o[4] = h2.x; o[5] = h2.y; o[6] = h3.x; o[7] = h3.y;
#undef GRU_STEP
#undef GATE_PAIR
#undef LOADX
#undef LO2
#undef HI2
}

// ---------- epilogue: 4 waves/block, 1 wave per b.  lane = (h = l&31, f-halfset = l>>5)
__global__ __launch_bounds__(256)
void post_kernel(const float* __restrict__ pre,     // [B,18,32] (f<17 valid)
                 const float* __restrict__ statics, // [B,4]
                 const float* __restrict__ demoW,   // [32,4]
                 const float* __restrict__ demob,   // [32]
                 const float* __restrict__ lnw,     // [18,32]
                 const float* __restrict__ lnb,     // [18,32]
                 const float* __restrict__ protos,  // [8,576]
                 const float* __restrict__ pnorm,   // [8]
                 const float* __restrict__ Wq,      // [32,8]
                 const float* __restrict__ bq,      // [32]
                 const float* __restrict__ Wk,      // [8,18]
                 const float* __restrict__ bk,      // [8]
                 const float* __restrict__ Wv,      // [8,18]
                 const float* __restrict__ bv,      // [8]
                 const float* __restrict__ outW,    // [32]
                 const float* __restrict__ outb,    // [1]
                 float* __restrict__ out_logits,    // [B]
                 float* __restrict__ out_dist,      // [B,8]
                 float* __restrict__ out_ht)        // [B,18,32]
{
    const int b     = blockIdx.x * 4 + (threadIdx.x >> 6);
    const int l     = threadIdx.x & 63;
    const int hl    = l & 31;
    const int fbase = (l >> 5) * 9;

    float v[9];
    #pragma unroll
    for (int j = 0; j < 9; ++j) {
        const int fj = fbase + j;
        if (fj == 17) {
            float acc = demob[hl];
            #pragma unroll
            for (int d = 0; d < 4; ++d)
                acc = fmaf(statics[b * 4 + d], demoW[hl * 4 + d], acc);
            v[j] = acc;
        } else {
            v[j] = pre[(size_t)b * 576 + fj * 32 + hl];
        }
    }

    float s = 0.0f, ss = 0.0f;
    #pragma unroll
    for (int j = 0; j < 9; ++j) { s += v[j]; ss = fmaf(v[j], v[j], ss); }
    #pragma unroll
    for (int m = 32; m; m >>= 1) { s += __shfl_xor(s, m); ss += __shfl_xor(ss, m); }
    const float mu  = s * (1.0f / 576.0f);
    const float var = ss * (1.0f / 576.0f) - mu * mu;
    const float rs  = frsq(var + 1e-5f);

    float nrm = 0.0f;
    #pragma unroll
    for (int j = 0; j < 9; ++j) {
        const int fj = fbase + j;
        float y = fmaf((v[j] - mu) * rs, lnw[fj * 32 + hl], lnb[fj * 32 + hl]);
        v[j] = y;
        out_ht[(size_t)b * 576 + fj * 32 + hl] = y;
        nrm = fmaf(y, y, nrm);
    }
    #pragma unroll
    for (int m = 32; m; m >>= 1) nrm += __shfl_xor(nrm, m);
    nrm = sqrtf(nrm);

    float dist[8];
    #pragma unroll
    for (int p = 0; p < Pnum; ++p) {
        float d = 0.0f;
        #pragma unroll
        for (int j = 0; j < 9; ++j)
            d = fmaf(v[j], protos[p * 576 + (fbase + j) * 32 + hl], d);
        #pragma unroll
        for (int m = 32; m; m >>= 1) d += __shfl_xor(d, m);
        dist[p] = d / fmaxf(nrm * pnorm[p], 1e-8f);
    }
    if (l == 0) {
        #pragma unroll
        for (int p = 0; p < Pnum; ++p) out_dist[(size_t)b * Pnum + p] = dist[p];
    }

    float q = bq[hl];
    #pragma unroll
    for (int p = 0; p < Pnum; ++p) q = fmaf(dist[p], Wq[hl * 8 + p], q);
    float Sq = q;
    #pragma unroll
    for (int m = 16; m; m >>= 1) Sq += __shfl_xor(Sq, m);

    float sf[9], so[9];
    #pragma unroll
    for (int j = 0; j < 9; ++j) {
        float t = v[j] * q;
        #pragma unroll
        for (int m = 16; m; m >>= 1) t += __shfl_xor(t, m);
        sf[j] = t;
    }
    #pragma unroll
    for (int j = 0; j < 9; ++j) so[j] = __shfl_xor(sf[j], 32);
    const int obase = 9 - fbase;

    float e[8];
    #pragma unroll
    for (int p = 0; p < Pnum; ++p) {
        float a = bk[p] * Sq;
        #pragma unroll
        for (int j = 0; j < 9; ++j) {
            a = fmaf(sf[j], Wk[p * FPn + fbase + j], a);
            a = fmaf(so[j], Wk[p * FPn + obase + j], a);
        }
        e[p] = a;
    }
    float mx = e[0];
    #pragma unroll
    for (int p = 1; p < Pnum; ++p) mx = fmaxf(mx, e[p]);
    float aw[8], den = 0.0f;
    #pragma unroll
    for (int p = 0; p < Pnum; ++p) { aw[p] = __expf(e[p] - mx); den += aw[p]; }
    const float rden = frcp(den);
    #pragma unroll
    for (int p = 0; p < Pnum; ++p) aw[p] *= rden;

    float cc = 0.0f;
    #pragma unroll
    for (int p = 0; p < Pnum; ++p) cc = fmaf(aw[p], bv[p], cc);
    float vb = 0.0f;
    #pragma unroll
    for (int j = 0; j < 9; ++j) {
        float wv = 0.0f;
        #pragma unroll
        for (int p = 0; p < Pnum; ++p) wv = fmaf(aw[p], Wv[p * FPn + fbase + j], wv);
        vb = fmaf(v[j], wv, vb);
    }
    vb += __shfl_xor(vb, 32);
    vb += cc;

    float lg = vb * outW[hl];
    #pragma unroll
    for (int m = 16; m; m >>= 1) lg += __shfl_xor(lg, m);
    lg = fsigmoid(lg + outb[0]);
    if (l == 0) out_logits[b] = lg;
}

extern "C" void kernel_launch(void* const* d_in, const int* in_sizes, int n_in,
                              void* d_out, int out_size, void* d_ws, size_t ws_size,
                              hipStream_t stream) {
    const float* x      = (const float*)d_in[0];
    const float* statics= (const float*)d_in[1];
    const float* Wih    = (const float*)d_in[2];
    const float* Whh    = (const float*)d_in[3];
    const float* bih    = (const float*)d_in[4];
    const float* bhh    = (const float*)d_in[5];
    const float* demoW  = (const float*)d_in[6];
    const float* demob  = (const float*)d_in[7];
    const float* lnw    = (const float*)d_in[8];
    const float* lnb    = (const float*)d_in[9];
    const float* protos = (const float*)d_in[10];
    const float* Wq     = (const float*)d_in[11];
    const float* bq     = (const float*)d_in[12];
    const float* Wk     = (const float*)d_in[13];
    const float* bk     = (const float*)d_in[14];
    const float* Wv     = (const float*)d_in[15];
    const float* bv     = (const float*)d_in[16];
    const float* outW   = (const float*)d_in[17];
    const float* outb   = (const float*)d_in[18];

    // ws layout: pre[B*576] f32 | pnorm[8] f32 | xT[F,T+TPAD,B] bf16
    float* pre   = (float*)d_ws;
    float* pnorm = pre + (size_t)Bsz * FPn * Hdim;
    unsigned short* xT = (unsigned short*)(pnorm + 8);
    const size_t need = ((size_t)Bsz * FPn * Hdim + 8) * 4
                      + (size_t)Fnum * (Tlen + TPAD) * Bsz * 2;
    const bool use_xt = (ws_size >= need);

    prep_pnorm_kernel<<<dim3(1), dim3(256), 0, stream>>>(protos, pnorm);

    if (use_xt) {
        xpose_kernel<<<dim3(Bsz / 64, Tlen), dim3(64), 0, stream>>>(x, xT);
        gru_mfma_kernel<1><<<dim3(Bsz / 16, Fnum), dim3(64), 0, stream>>>(
            x, xT, Wih, Whh, bih, bhh, pre);
    } else {
        gru_mfma_kernel<0><<<dim3(Bsz / 16, Fnum), dim3(64), 0, stream>>>(
            x, xT, Wih, Whh, bih, bhh, pre);
    }

    float* out_logits = (float*)d_out;
    float* out_dist   = out_logits + Bsz;
    float* out_ht     = out_dist + (size_t)Bsz * Pnum;

    post_kernel<<<dim3(Bsz / 4), dim3(256), 0, stream>>>(
        pre, statics, demoW, demob, lnw, lnb, protos, pnorm,
        Wq, bq, Wk, bk, Wv, bv, outW, outb,
        out_logits, out_dist, out_ht);
}